// Round 13
// baseline (335.927 us; speedup 1.0000x reference)
//
#include <hip/hip_runtime.h>
#include <hip/hip_fp16.h>
#include <math.h>

#define NNODES 50000
#define IND    128
#define NH     8
#define OD     16
#define NEDGE  1600000
#define NOUT   272           // 128 K + 128 V + 16 Qsum
#define NBUCK  391           // dst>>7 buckets (128 nodes each)
#define BCAP   4608          // per-bucket output capacity
#define SCAP   56            // per (bucket,chunk) cell capacity
#define P1B    196           // edge chunks of 8192
#define PB2    782           // ceil(50000/64) proj tiles

typedef _Float16 half8 __attribute__((ext_vector_type(8)));
typedef _Float16 h2t   __attribute__((ext_vector_type(2)));
typedef float    floatx4 __attribute__((ext_vector_type(4)));

static __device__ __forceinline__ h2t u2h(unsigned int u) {
    union { unsigned int u; h2t h; } x; x.u = u; return x.h;
}
static __device__ __forceinline__ float2 u2f2(unsigned int u) {
    union { unsigned int u; __half2 h; } x; x.u = u;
    return __half22float2(x.h);
}

// ---------------- K1: atomic-free bucket scatter + W16s/b_all build -----------
// (unchanged from R12) Blocks [0,P1B): 8192 edges; rank = LDS atomicAdd
// return; deterministic cell writes; no global atomics. Block P1B: W16s+b_all.
__global__ __launch_bounds__(256) void k1_scatter_w16(
    const int* __restrict__ src, const int* __restrict__ dst,
    unsigned int* __restrict__ ebuck, unsigned short* __restrict__ counts,
    const float* __restrict__ Qw, const float* __restrict__ Qb,
    const float* __restrict__ Kw, const float* __restrict__ Kb,
    const float* __restrict__ Vw, const float* __restrict__ Vb,
    _Float16* __restrict__ W16s, float* __restrict__ b_all)
{
    const int t = threadIdx.x;

    if (blockIdx.x < P1B) {
        __shared__ int bcnt[NBUCK];
        for (int i = t; i < NBUCK; i += 256) bcnt[i] = 0;
        __syncthreads();

        const int blk = blockIdx.x;
        const int e0  = blk * 8192;
        const int nq  = (min(8192, NEDGE - e0)) >> 2;
        const int4* s4 = (const int4*)(src + e0);
        const int4* d4 = (const int4*)(dst + e0);

        uint4 ev4[8];
        unsigned int rkp[16];
#pragma unroll
        for (int j = 0; j < 8; j++) {
            int qi = j * 256 + t;
            if (qi < nq) {
                int4 ss = s4[qi];
                int4 dd = d4[qi];
                unsigned int v0 = (((unsigned)dd.x >> 7) << 23) | ((unsigned)ss.x << 7) | ((unsigned)dd.x & 127u);
                unsigned int v1 = (((unsigned)dd.y >> 7) << 23) | ((unsigned)ss.y << 7) | ((unsigned)dd.y & 127u);
                unsigned int v2 = (((unsigned)dd.z >> 7) << 23) | ((unsigned)ss.z << 7) | ((unsigned)dd.z & 127u);
                unsigned int v3 = (((unsigned)dd.w >> 7) << 23) | ((unsigned)ss.w << 7) | ((unsigned)dd.w & 127u);
                ev4[j] = make_uint4(v0, v1, v2, v3);
                unsigned r0 = atomicAdd(&bcnt[v0 >> 23], 1);
                unsigned r1 = atomicAdd(&bcnt[v1 >> 23], 1);
                unsigned r2 = atomicAdd(&bcnt[v2 >> 23], 1);
                unsigned r3 = atomicAdd(&bcnt[v3 >> 23], 1);
                rkp[2 * j]     = r0 | (r1 << 16);
                rkp[2 * j + 1] = r2 | (r3 << 16);
            }
        }
        __syncthreads();
#pragma unroll
        for (int j = 0; j < 8; j++) {
            int qi = j * 256 + t;
            if (qi < nq) {
                uint4 v = ev4[j];
                unsigned p0 = rkp[2 * j], p1 = rkp[2 * j + 1];
                unsigned r0 = p0 & 0xFFFFu, r1 = p0 >> 16;
                unsigned r2 = p1 & 0xFFFFu, r3 = p1 >> 16;
                if (r0 < SCAP) ebuck[((size_t)(v.x >> 23) * P1B + blk) * SCAP + r0] = v.x;
                if (r1 < SCAP) ebuck[((size_t)(v.y >> 23) * P1B + blk) * SCAP + r1] = v.y;
                if (r2 < SCAP) ebuck[((size_t)(v.z >> 23) * P1B + blk) * SCAP + r2] = v.z;
                if (r3 < SCAP) ebuck[((size_t)(v.w >> 23) * P1B + blk) * SCAP + r3] = v.w;
            }
        }
        __syncthreads();
        for (int i = t; i < NBUCK; i += 256)
            counts[(size_t)blk * NBUCK + i] = (unsigned short)min(bcnt[i], SCAP);
        return;
    }

    // W16s swizzled so proj B-frag (ti,ks) is lane-contiguous. Plus b_all.
    for (int i = t; i < NOUT * IND; i += 256) {
        int r = i >> 7, c = i & 127;
        float v;
        if (r < 128)       v = Kw[r * IND + c];
        else if (r < 256)  v = Vw[(r - 128) * IND + c];
        else {
            v = 0.f;
#pragma unroll
            for (int hh = 0; hh < NH; hh++) v += Qw[((hh << 4) + (r - 256)) * IND + c];
        }
        int ti = r >> 4, cl = r & 15, ks = c >> 5, quad = (c >> 3) & 3, e = c & 7;
        W16s[((((ti << 2) + ks) << 6) + quad * 16 + cl) * 8 + e] = (_Float16)v;
    }
    for (int i = t; i < NOUT; i += 256) {
        float v;
        if (i < 128)      v = Kb[i];
        else if (i < 256) v = Vb[i - 128];
        else {
            v = 0.f;
#pragma unroll
            for (int hh = 0; hh < NH; hh++) v += Qb[(hh << 4) + (i - 256)];
        }
        b_all[i] = v;
    }
}

// ---------------- K2: MFMA proj (head-major K/V output) + grouping ------------
// Proj writes head-major tables: K tile ti (0-7) -> head ti dim cl;
// V tile ti (8-15) -> head ti-8 dim cl. Group phase unchanged from R12.
__global__ __launch_bounds__(256) void k2_proj_group(
    const float* __restrict__ hmat,
    const _Float16* __restrict__ W16s, const float* __restrict__ b_all,
    _Float16* __restrict__ Ktab, _Float16* __restrict__ Vtab,
    _Float16* __restrict__ Qs16,
    const unsigned int* __restrict__ ebuck, const unsigned short* __restrict__ counts,
    int* __restrict__ offs, int* __restrict__ count,
    unsigned short* __restrict__ eidx16)
{
    const int t = threadIdx.x;

    if (blockIdx.x < PB2) {                            // ---- projection -------
        const int wave = t >> 6;
        const int l    = t & 63;
        const int cl   = l & 15;
        const int quad = l >> 4;
        const int m0   = blockIdx.x * 64 + wave * 16;

        const int arow = min(m0 + cl, NNODES - 1);
        const float* ab = hmat + (size_t)arow * IND + quad * 8;
        half8 afrag[4];
#pragma unroll
        for (int ks = 0; ks < 4; ks++) {
            float4 x = *(const float4*)(ab + ks * 32);
            float4 y = *(const float4*)(ab + ks * 32 + 4);
            half8 o;
            o[0] = (_Float16)x.x; o[1] = (_Float16)x.y;
            o[2] = (_Float16)x.z; o[3] = (_Float16)x.w;
            o[4] = (_Float16)y.x; o[5] = (_Float16)y.y;
            o[6] = (_Float16)y.z; o[7] = (_Float16)y.w;
            afrag[ks] = o;
        }

        const int rowbase = m0 + quad * 4;
        const half8* Wf = (const half8*)W16s;

#pragma unroll 4
        for (int ti = 0; ti < 17; ti++) {
            floatx4 acc = {0.f, 0.f, 0.f, 0.f};
#pragma unroll
            for (int ks = 0; ks < 4; ks++)
                acc = __builtin_amdgcn_mfma_f32_16x16x32_f16(
                    afrag[ks], Wf[(((ti << 2) + ks) << 6) + l], acc, 0, 0, 0);

            const float bias = b_all[ti * 16 + cl];
            if (ti < 8) {                              // K head ti, dim cl
#pragma unroll
                for (int r = 0; r < 4; r++) {
                    int node = rowbase + r;
                    if (node < NNODES)
                        Ktab[((size_t)ti * NNODES + node) * OD + cl] =
                            (_Float16)(acc[r] + bias);
                }
            } else if (ti < 16) {                      // V head ti-8, dim cl
#pragma unroll
                for (int r = 0; r < 4; r++) {
                    int node = rowbase + r;
                    if (node < NNODES)
                        Vtab[((size_t)(ti - 8) * NNODES + node) * OD + cl] =
                            (_Float16)(acc[r] + bias);
                }
            } else {
#pragma unroll
                for (int r = 0; r < 4; r++) {
                    int node = rowbase + r;
                    if (node < NNODES)
                        Qs16[(size_t)node * OD + cl] = (_Float16)(acc[r] + bias);
                }
            }
        }
        return;
    }

    // ---- grouping (unchanged R12) -------------------------------------------
    __shared__ int esh[BCAP];
    __shared__ int csh[256];
    __shared__ int cbase[256];
    __shared__ int sdc[256];
    __shared__ int cnt[128];
    __shared__ int sdn[128];
    __shared__ int base128[128];

    const int b = blockIdx.x - PB2;

    csh[t] = (t < P1B) ? (int)counts[(size_t)t * NBUCK + b] : 0;
    __syncthreads();
    sdc[t] = csh[t];
    __syncthreads();
    for (int ofs = 1; ofs < 256; ofs <<= 1) {
        int x = (t >= ofs) ? sdc[t - ofs] : 0;
        __syncthreads();
        sdc[t] += x;
        __syncthreads();
    }
    cbase[t] = sdc[t] - csh[t];
    __syncthreads();
    const int Eb = sdc[P1B - 1];

    const unsigned int* cells = ebuck + (size_t)b * P1B * SCAP;
    for (int idx = t; idx < P1B * SCAP; idx += 256) {
        int j = idx / SCAP;
        int r = idx - j * SCAP;
        if (r < csh[j]) {
            int p = cbase[j] + r;
            if (p < BCAP) esh[p] = (int)cells[idx];
        }
    }
    if (t < 128) cnt[t] = 0;
    __syncthreads();

    int rk[18];
#pragma unroll
    for (int j = 0; j < 18; j++) {
        int i = j * 256 + t;
        if (i < Eb) rk[j] = atomicAdd(&cnt[esh[i] & 127], 1);
    }
    __syncthreads();

    if (t < 128) sdn[t] = cnt[t];
    __syncthreads();
    for (int ofs = 1; ofs < 128; ofs <<= 1) {
        int x = 0;
        if (t < 128 && t >= ofs) x = sdn[t - ofs];
        __syncthreads();
        if (t < 128) sdn[t] += x;
        __syncthreads();
    }
    if (t < 128) {
        int excl = sdn[t] - cnt[t];
        base128[t] = excl;
        int node = (b << 7) + t;
        if (node < NNODES) { offs[node] = b * BCAP + excl; count[node] = cnt[t]; }
    }
    __syncthreads();

#pragma unroll
    for (int j = 0; j < 18; j++) {
        int i = j * 256 + t;
        if (i < Eb) {
            int v = esh[i];
            eidx16[(size_t)b * BCAP + base128[v & 127] + rk[j]] =
                (unsigned short)((v >> 7) & 0xFFFFu);
        }
    }
}

// ---------------- K3: head-sliced XCD-pinned gather ---------------------------
// Block bid: head h = bid&7 (-> XCD h via round-robin), nodes (bid>>3)*4+wave.
// Per-XCD hot set = Kh + Vh = 3.2 MB < 4 MB L2. Lane l: edge-group g=l>>2
// (16 edges in flight), dim-quad j4=l&3 (dims 4*j4..+3). Score: 2 fdot2 +
// xor{1,2}; V accumulated fp32. Cross-group reduce xor{4,8,16,32}; lanes 0-3
// write z-normalized fp16x4 to hout[h][n][16] (NT store).
__global__ __launch_bounds__(256) void k3_gather(
    const _Float16* __restrict__ Ktab, const _Float16* __restrict__ Vtab,
    const _Float16* __restrict__ Qs16,
    const int* __restrict__ offs, const int* __restrict__ count,
    const unsigned short* __restrict__ eidx16,
    _Float16* __restrict__ hout)
{
    const int h  = blockIdx.x & 7;
    const int n  = (blockIdx.x >> 3) * 4 + (threadIdx.x >> 6);
    const int l  = threadIdx.x & 63;
    const int g  = l >> 2;
    const int j4 = l & 3;

    const _Float16* Kh = Ktab + (size_t)h * NNODES * OD;
    const _Float16* Vh = Vtab + (size_t)h * NNODES * OD;

    const uint2 qv = *(const uint2*)(Qs16 + (size_t)n * OD + j4 * 4);

    const int off   = offs[n];
    const int total = count[n] + 1;                  // + self-loop

    float a0 = 0.f, a1 = 0.f, a2 = 0.f, a3 = 0.f, z = 0.f;

    for (int base = 0; base < total; base += 64) {
        const int gi = base + l;
        int id = n;                                  // gi==0 -> self-loop
        if (gi > 0 && gi < total)
            id = (int)__builtin_nontemporal_load(eidx16 + off + gi - 1);
        const int steps = min(64, total - base);

        for (int r = 0; r < steps; r += 16) {
            const int e = r + g;                     // e <= 63
            const int sid = __shfl(id, e, 64);
            const uint2 kk = *(const uint2*)(Kh + (size_t)sid * OD + j4 * 4);
            const uint2 vv = *(const uint2*)(Vh + (size_t)sid * OD + j4 * 4);

            float p = __builtin_amdgcn_fdot2(u2h(kk.y), u2h(qv.y),
                      __builtin_amdgcn_fdot2(u2h(kk.x), u2h(qv.x), 0.f, false), false);
            p += __shfl_xor(p, 1, 64);
            p += __shfl_xor(p, 2, 64);
            float sc = __expf(fminf(5.f, fmaxf(-5.f, p * 0.25f)));
            if (e >= steps) sc = 0.f;
            z += sc;
            float2 f0 = u2f2(vv.x);
            float2 f1 = u2f2(vv.y);
            a0 = fmaf(f0.x, sc, a0); a1 = fmaf(f0.y, sc, a1);
            a2 = fmaf(f1.x, sc, a2); a3 = fmaf(f1.y, sc, a3);
        }
    }

    // reduce across the 16 edge-groups (l bits 2..5)
#pragma unroll
    for (int m = 4; m <= 32; m <<= 1) {
        a0 += __shfl_xor(a0, m, 64);
        a1 += __shfl_xor(a1, m, 64);
        a2 += __shfl_xor(a2, m, 64);
        a3 += __shfl_xor(a3, m, 64);
        z  += __shfl_xor(z,  m, 64);
    }

    if (l < 4) {
        const float inv = 1.f / z;
        h2t p0, p1;
        p0.x = (_Float16)(a0 * inv); p0.y = (_Float16)(a1 * inv);
        p1.x = (_Float16)(a2 * inv); p1.y = (_Float16)(a3 * inv);
        union { struct { h2t a, b; } h; unsigned long long u; } pk;
        pk.h.a = p0; pk.h.b = p1;
        __builtin_nontemporal_store(pk.u,
            (unsigned long long*)(hout + ((size_t)h * NNODES + n) * OD + l * 4));
    }
}

// ---------------- K4: combine heads -> out ------------------------------------
__global__ __launch_bounds__(256) void k4_combine(
    const _Float16* __restrict__ hout, float* __restrict__ out)
{
    const int t = blockIdx.x * 256 + threadIdx.x;
    if (t >= NNODES * 4) return;
    const int n = t >> 2, q = t & 3;
    float sx = 0.f, sy = 0.f, sz = 0.f, sw = 0.f;
#pragma unroll
    for (int h = 0; h < NH; h++) {
        uint2 u = *(const uint2*)(hout + ((size_t)h * NNODES + n) * OD + q * 4);
        float2 f0 = u2f2(u.x);
        float2 f1 = u2f2(u.y);
        sx += f0.x; sy += f0.y; sz += f1.x; sw += f1.y;
    }
    ((float4*)out)[t] = make_float4(sx * 0.125f, sy * 0.125f, sz * 0.125f, sw * 0.125f);
}

// ---------------- launch ------------------------------------------------------
extern "C" void kernel_launch(void* const* d_in, const int* in_sizes, int n_in,
                              void* d_out, int out_size, void* d_ws, size_t ws_size,
                              hipStream_t stream)
{
    const float* h  = (const float*)d_in[0];
    const float* Qw = (const float*)d_in[1];
    const float* Qb = (const float*)d_in[2];
    const float* Kw = (const float*)d_in[3];
    const float* Kb = (const float*)d_in[4];
    const float* Vw = (const float*)d_in[5];
    const float* Vb = (const float*)d_in[6];
    const int*   src = (const int*)d_in[7];
    const int*   dst = (const int*)d_in[8];

    char* ws = (char*)d_ws;
    _Float16* W16s  = (_Float16*)ws;                   ws += (size_t)NOUT * IND * 2;
    float*    b_all = (float*)ws;                      ws += 288 * 4;
    _Float16* Ktab  = (_Float16*)ws;                   ws += (size_t)NH * NNODES * OD * 2;  // 12.8 MB
    _Float16* Vtab  = (_Float16*)ws;                   ws += (size_t)NH * NNODES * OD * 2;  // 12.8 MB
    _Float16* Qs16  = (_Float16*)ws;                   ws += (size_t)NNODES * OD * 2;
    _Float16* hout  = (_Float16*)ws;                   ws += (size_t)NH * NNODES * OD * 2;  // 12.8 MB
    int*      offs   = (int*)ws;                       ws += (size_t)NNODES * 4;
    int*      count  = (int*)ws;                       ws += (size_t)NNODES * 4;
    unsigned short* counts = (unsigned short*)ws;      ws += (size_t)P1B * NBUCK * 2 + 64;
    unsigned int*   ebuck  = (unsigned int*)ws;        ws += (size_t)NBUCK * P1B * SCAP * 4;
    unsigned short* eidx16 = (unsigned short*)ws;      ws += (size_t)NBUCK * BCAP * 2;

    k1_scatter_w16<<<P1B + 1, 256, 0, stream>>>(
        src, dst, ebuck, counts, Qw, Qb, Kw, Kb, Vw, Vb, W16s, b_all);

    k2_proj_group<<<PB2 + NBUCK, 256, 0, stream>>>(
        h, W16s, b_all, Ktab, Vtab, Qs16, ebuck, counts, offs, count, eidx16);

    k3_gather<<<(NNODES / 4) * NH, 256, 0, stream>>>(
        Ktab, Vtab, Qs16, offs, count, eidx16, hout);

    k4_combine<<<(NNODES * 4 + 255) / 256, 256, 0, stream>>>(hout, (float*)d_out);
}

// Round 14
// 264.567 us; speedup vs baseline: 1.2697x; 1.2697x over previous
//
#include <hip/hip_runtime.h>
#include <hip/hip_fp16.h>
#include <math.h>

#define NNODES 50000
#define IND    128
#define NH     8
#define OD     16
#define NEDGE  1600000
#define NOUT   272           // 128 K + 128 V + 16 Qsum
#define NBUCK  391           // dst>>7 buckets (128 nodes each)
#define BCAP   4608          // per-bucket output capacity
#define SCAP   56            // per (bucket,chunk) cell capacity
#define P1B    196           // edge chunks of 8192
#define PB2    782           // ceil(50000/64) proj tiles

typedef _Float16 half8 __attribute__((ext_vector_type(8)));
typedef _Float16 h2t   __attribute__((ext_vector_type(2)));
typedef float    floatx4 __attribute__((ext_vector_type(4)));

static __device__ __forceinline__ h2t u2h(unsigned int u) {
    union { unsigned int u; h2t h; } x; x.u = u; return x.h;
}
// acc[d] += vA[d]*scA + vB[d]*scB for 8 dims, fp32 accumulators.
static __device__ __forceinline__ void vacc8(uint4 vA, uint4 vB, h2t sc2, float* acc) {
    unsigned lo, hi;
    lo = __builtin_amdgcn_perm(vB.x, vA.x, 0x05040100u);
    hi = __builtin_amdgcn_perm(vB.x, vA.x, 0x07060302u);
    acc[0] = __builtin_amdgcn_fdot2(u2h(lo), sc2, acc[0], false);
    acc[1] = __builtin_amdgcn_fdot2(u2h(hi), sc2, acc[1], false);
    lo = __builtin_amdgcn_perm(vB.y, vA.y, 0x05040100u);
    hi = __builtin_amdgcn_perm(vB.y, vA.y, 0x07060302u);
    acc[2] = __builtin_amdgcn_fdot2(u2h(lo), sc2, acc[2], false);
    acc[3] = __builtin_amdgcn_fdot2(u2h(hi), sc2, acc[3], false);
    lo = __builtin_amdgcn_perm(vB.z, vA.z, 0x05040100u);
    hi = __builtin_amdgcn_perm(vB.z, vA.z, 0x07060302u);
    acc[4] = __builtin_amdgcn_fdot2(u2h(lo), sc2, acc[4], false);
    acc[5] = __builtin_amdgcn_fdot2(u2h(hi), sc2, acc[5], false);
    lo = __builtin_amdgcn_perm(vB.w, vA.w, 0x05040100u);
    hi = __builtin_amdgcn_perm(vB.w, vA.w, 0x07060302u);
    acc[6] = __builtin_amdgcn_fdot2(u2h(lo), sc2, acc[6], false);
    acc[7] = __builtin_amdgcn_fdot2(u2h(hi), sc2, acc[7], false);
}
static __device__ __forceinline__ float qdot(uint4 k, uint4 q, float p) {
    p = __builtin_amdgcn_fdot2(u2h(k.x), u2h(q.x), p, false);
    p = __builtin_amdgcn_fdot2(u2h(k.y), u2h(q.y), p, false);
    p = __builtin_amdgcn_fdot2(u2h(k.z), u2h(q.z), p, false);
    p = __builtin_amdgcn_fdot2(u2h(k.w), u2h(q.w), p, false);
    return p;
}

// ---------------- K1: atomic-free bucket scatter + W16s/b_all build -----------
// (unchanged R12) Blocks [0,P1B): 8192 edges; rank = LDS atomicAdd return;
// deterministic cell writes; no global atomics. Block P1B: W16s + b_all.
__global__ __launch_bounds__(256) void k1_scatter_w16(
    const int* __restrict__ src, const int* __restrict__ dst,
    unsigned int* __restrict__ ebuck, unsigned short* __restrict__ counts,
    const float* __restrict__ Qw, const float* __restrict__ Qb,
    const float* __restrict__ Kw, const float* __restrict__ Kb,
    const float* __restrict__ Vw, const float* __restrict__ Vb,
    _Float16* __restrict__ W16s, float* __restrict__ b_all)
{
    const int t = threadIdx.x;

    if (blockIdx.x < P1B) {
        __shared__ int bcnt[NBUCK];
        for (int i = t; i < NBUCK; i += 256) bcnt[i] = 0;
        __syncthreads();

        const int blk = blockIdx.x;
        const int e0  = blk * 8192;
        const int nq  = (min(8192, NEDGE - e0)) >> 2;
        const int4* s4 = (const int4*)(src + e0);
        const int4* d4 = (const int4*)(dst + e0);

        uint4 ev4[8];
        unsigned int rkp[16];
#pragma unroll
        for (int j = 0; j < 8; j++) {
            int qi = j * 256 + t;
            if (qi < nq) {
                int4 ss = s4[qi];
                int4 dd = d4[qi];
                unsigned int v0 = (((unsigned)dd.x >> 7) << 23) | ((unsigned)ss.x << 7) | ((unsigned)dd.x & 127u);
                unsigned int v1 = (((unsigned)dd.y >> 7) << 23) | ((unsigned)ss.y << 7) | ((unsigned)dd.y & 127u);
                unsigned int v2 = (((unsigned)dd.z >> 7) << 23) | ((unsigned)ss.z << 7) | ((unsigned)dd.z & 127u);
                unsigned int v3 = (((unsigned)dd.w >> 7) << 23) | ((unsigned)ss.w << 7) | ((unsigned)dd.w & 127u);
                ev4[j] = make_uint4(v0, v1, v2, v3);
                unsigned r0 = atomicAdd(&bcnt[v0 >> 23], 1);
                unsigned r1 = atomicAdd(&bcnt[v1 >> 23], 1);
                unsigned r2 = atomicAdd(&bcnt[v2 >> 23], 1);
                unsigned r3 = atomicAdd(&bcnt[v3 >> 23], 1);
                rkp[2 * j]     = r0 | (r1 << 16);
                rkp[2 * j + 1] = r2 | (r3 << 16);
            }
        }
        __syncthreads();
#pragma unroll
        for (int j = 0; j < 8; j++) {
            int qi = j * 256 + t;
            if (qi < nq) {
                uint4 v = ev4[j];
                unsigned p0 = rkp[2 * j], p1 = rkp[2 * j + 1];
                unsigned r0 = p0 & 0xFFFFu, r1 = p0 >> 16;
                unsigned r2 = p1 & 0xFFFFu, r3 = p1 >> 16;
                if (r0 < SCAP) ebuck[((size_t)(v.x >> 23) * P1B + blk) * SCAP + r0] = v.x;
                if (r1 < SCAP) ebuck[((size_t)(v.y >> 23) * P1B + blk) * SCAP + r1] = v.y;
                if (r2 < SCAP) ebuck[((size_t)(v.z >> 23) * P1B + blk) * SCAP + r2] = v.z;
                if (r3 < SCAP) ebuck[((size_t)(v.w >> 23) * P1B + blk) * SCAP + r3] = v.w;
            }
        }
        __syncthreads();
        for (int i = t; i < NBUCK; i += 256)
            counts[(size_t)blk * NBUCK + i] = (unsigned short)min(bcnt[i], SCAP);
        return;
    }

    // W16s swizzled so proj B-frag (ti,ks) is lane-contiguous. Plus b_all.
    for (int i = t; i < NOUT * IND; i += 256) {
        int r = i >> 7, c = i & 127;
        float v;
        if (r < 128)       v = Kw[r * IND + c];
        else if (r < 256)  v = Vw[(r - 128) * IND + c];
        else {
            v = 0.f;
#pragma unroll
            for (int hh = 0; hh < NH; hh++) v += Qw[((hh << 4) + (r - 256)) * IND + c];
        }
        int ti = r >> 4, cl = r & 15, ks = c >> 5, quad = (c >> 3) & 3, e = c & 7;
        W16s[((((ti << 2) + ks) << 6) + quad * 16 + cl) * 8 + e] = (_Float16)v;
    }
    for (int i = t; i < NOUT; i += 256) {
        float v;
        if (i < 128)      v = Kb[i];
        else if (i < 256) v = Vb[i - 128];
        else {
            v = 0.f;
#pragma unroll
            for (int hh = 0; hh < NH; hh++) v += Qb[(hh << 4) + (i - 256)];
        }
        b_all[i] = v;
    }
}

// ---------------- K2: MFMA proj (LDS-staged coalesced stores) + grouping ------
// Blocks [0,PB2): projection; tile outputs staged in a 34 KB LDS image laid
// out identically to global KVbuf rows, then streamed out as dwordx4.
// Blocks [PB2,..): per-bucket grouping (R12), sharing the LDS via union.
__global__ __launch_bounds__(256) void k2_proj_group(
    const float* __restrict__ hmat,
    const _Float16* __restrict__ W16s, const float* __restrict__ b_all,
    __half* __restrict__ KVbuf, _Float16* __restrict__ Qs16,
    const unsigned int* __restrict__ ebuck, const unsigned short* __restrict__ counts,
    int* __restrict__ offs, int* __restrict__ count,
    unsigned short* __restrict__ eidx16)
{
    __shared__ __align__(16) unsigned char smem[35072];
    const int t = threadIdx.x;

    if (blockIdx.x < PB2) {                            // ---- projection -------
        _Float16* kvs = (_Float16*)smem;               // [64][256]  32 KB
        _Float16* qss = (_Float16*)(smem + 32768);     // [64][16]    2 KB

        const int wave = t >> 6;
        const int l    = t & 63;
        const int cl   = l & 15;
        const int quad = l >> 4;
        const int m0   = blockIdx.x * 64 + wave * 16;

        const int arow = min(m0 + cl, NNODES - 1);     // clamp OOB tail rows
        const float* ab = hmat + (size_t)arow * IND + quad * 8;
        half8 afrag[4];
#pragma unroll
        for (int ks = 0; ks < 4; ks++) {
            float4 x = *(const float4*)(ab + ks * 32);
            float4 y = *(const float4*)(ab + ks * 32 + 4);
            half8 o;
            o[0] = (_Float16)x.x; o[1] = (_Float16)x.y;
            o[2] = (_Float16)x.z; o[3] = (_Float16)x.w;
            o[4] = (_Float16)y.x; o[5] = (_Float16)y.y;
            o[6] = (_Float16)y.z; o[7] = (_Float16)y.w;
            afrag[ks] = o;
        }

        const int nl0 = wave * 16 + quad * 4;          // local node base
        const half8* Wf = (const half8*)W16s;

#pragma unroll 4
        for (int ti = 0; ti < 17; ti++) {
            floatx4 acc = {0.f, 0.f, 0.f, 0.f};
#pragma unroll
            for (int ks = 0; ks < 4; ks++)
                acc = __builtin_amdgcn_mfma_f32_16x16x32_f16(
                    afrag[ks], Wf[(((ti << 2) + ks) << 6) + l], acc, 0, 0, 0);

            const float bias = b_all[ti * 16 + cl];
            if (ti < 16) {
                const int col = ti * 16 + cl;
#pragma unroll
                for (int r = 0; r < 4; r++)
                    kvs[(nl0 + r) * 256 + col] = (_Float16)(acc[r] + bias);
            } else {
#pragma unroll
                for (int r = 0; r < 4; r++)
                    qss[(nl0 + r) * OD + cl] = (_Float16)(acc[r] + bias);
            }
        }
        __syncthreads();

        // coalesced stores: 64 rows x 512 B KV (2048 uint4), 64 x 32 B Qs
        const int n0 = blockIdx.x * 64;
        uint4* kvg = (uint4*)(KVbuf + (size_t)n0 * 256);
        const uint4* kvl = (const uint4*)kvs;
#pragma unroll
        for (int it = 0; it < 8; it++) {
            int i = it * 256 + t;
            if (n0 + (i >> 5) < NNODES) kvg[i] = kvl[i];
        }
        uint4* qsg = (uint4*)(Qs16 + (size_t)n0 * OD);
        const uint4* qsl = (const uint4*)qss;
        if (t < 128 && n0 + (t >> 1) < NNODES) qsg[t] = qsl[t];
        return;
    }

    // ---- grouping (R12, pointers into smem) ---------------------------------
    int* esh   = (int*)smem;                 // BCAP = 18432 B
    int* csh   = (int*)(smem + 18432);       // 256
    int* cbase = (int*)(smem + 19456);       // 256
    int* sdc   = (int*)(smem + 20480);       // 256
    int* cnt   = (int*)(smem + 21504);       // 128
    int* sdn   = (int*)(smem + 22016);       // 128
    int* base128 = (int*)(smem + 22528);     // 128

    const int b = blockIdx.x - PB2;

    csh[t] = (t < P1B) ? (int)counts[(size_t)t * NBUCK + b] : 0;
    __syncthreads();
    sdc[t] = csh[t];
    __syncthreads();
    for (int ofs = 1; ofs < 256; ofs <<= 1) {
        int x = (t >= ofs) ? sdc[t - ofs] : 0;
        __syncthreads();
        sdc[t] += x;
        __syncthreads();
    }
    cbase[t] = sdc[t] - csh[t];
    __syncthreads();
    const int Eb = sdc[P1B - 1];

    const unsigned int* cells = ebuck + (size_t)b * P1B * SCAP;
    for (int idx = t; idx < P1B * SCAP; idx += 256) {
        int j = idx / SCAP;
        int r = idx - j * SCAP;
        if (r < csh[j]) {
            int p = cbase[j] + r;
            if (p < BCAP) esh[p] = (int)cells[idx];
        }
    }
    if (t < 128) cnt[t] = 0;
    __syncthreads();

    int rk[18];
#pragma unroll
    for (int j = 0; j < 18; j++) {
        int i = j * 256 + t;
        if (i < Eb) rk[j] = atomicAdd(&cnt[esh[i] & 127], 1);
    }
    __syncthreads();

    if (t < 128) sdn[t] = cnt[t];
    __syncthreads();
    for (int ofs = 1; ofs < 128; ofs <<= 1) {
        int x = 0;
        if (t < 128 && t >= ofs) x = sdn[t - ofs];
        __syncthreads();
        if (t < 128) sdn[t] += x;
        __syncthreads();
    }
    if (t < 128) {
        int excl = sdn[t] - cnt[t];
        base128[t] = excl;
        int node = (b << 7) + t;
        if (node < NNODES) { offs[node] = b * BCAP + excl; count[node] = cnt[t]; }
    }
    __syncthreads();

#pragma unroll
    for (int j = 0; j < 18; j++) {
        int i = j * 256 + t;
        if (i < Eb) {
            int v = esh[i];
            eidx16[(size_t)b * BCAP + base128[v & 127] + rk[j]] =
                (unsigned short)((v >> 7) & 0xFFFFu);
        }
    }
}

// ---------------- K3: gather-reduce, 16 lanes/edge (R12-verified) -------------
__global__ __launch_bounds__(256) void k3_gather(
    const uint4* __restrict__ KV4, const uint4* __restrict__ Qs16u4,
    const int* __restrict__ offs, const int* __restrict__ count,
    const unsigned short* __restrict__ eidx16,
    float* __restrict__ out)
{
    const int n = blockIdx.x * 4 + (threadIdx.x >> 6);
    const int l = threadIdx.x & 63;
    if (n >= NNODES) return;

    const int lh = l & 15;
    const int eg = l >> 4;
    const int la = 2 * eg, lb = 2 * eg + 1;

    const uint4 qh = Qs16u4[n * 2 + (lh & 1)];

    const int off   = offs[n];
    const int total = count[n] + 1;                  // + self-loop

    float acc[8] = {0.f, 0.f, 0.f, 0.f, 0.f, 0.f, 0.f, 0.f};
    float zacc = 0.f;

    for (int base = 0; base < total; base += 64) {
        const int gi = base + l;
        int id = n;                                  // gi==0 -> self-loop
        if (gi > 0) id = (gi < total) ? (int)eidx16[off + gi - 1] : 0;
        const int steps = min(64, total - base);

        int sA = __shfl(id, la, 64), sB = __shfl(id, lb, 64);
        uint4 kA0 = KV4[(size_t)sA * 32 + lh];
        uint4 vA0 = KV4[(size_t)sA * 32 + 16 + lh];
        uint4 kB0 = KV4[(size_t)sB * 32 + lh];
        uint4 vB0 = KV4[(size_t)sB * 32 + 16 + lh];
        int n1a = 8 + la, n1b = 8 + lb;
        int sA1 = __shfl(id, (n1a < 64) ? n1a : 0, 64);
        int sB1 = __shfl(id, (n1b < 64) ? n1b : 0, 64);
        uint4 kA1 = KV4[(size_t)sA1 * 32 + lh];
        uint4 vA1 = KV4[(size_t)sA1 * 32 + 16 + lh];
        uint4 kB1 = KV4[(size_t)sB1 * 32 + lh];
        uint4 vB1 = KV4[(size_t)sB1 * 32 + 16 + lh];

        for (int j = 0; j < steps; j += 8) {
            uint4 kA2, vA2, kB2, vB2;
            if (j + 16 < steps) {
                int n2a = j + 16 + la, n2b = j + 16 + lb;
                int sA2 = __shfl(id, (n2a < 64) ? n2a : 0, 64);
                int sB2 = __shfl(id, (n2b < 64) ? n2b : 0, 64);
                kA2 = KV4[(size_t)sA2 * 32 + lh];
                vA2 = KV4[(size_t)sA2 * 32 + 16 + lh];
                kB2 = KV4[(size_t)sB2 * 32 + lh];
                vB2 = KV4[(size_t)sB2 * 32 + 16 + lh];
            }
            float pA = qdot(kA0, qh, 0.f);
            float pB = qdot(kB0, qh, 0.f);
            pA += __shfl_xor(pA, 1, 64);
            pB += __shfl_xor(pB, 1, 64);
            float scA = __expf(fminf(5.f, fmaxf(-5.f, pA * 0.25f)));
            float scB = __expf(fminf(5.f, fmaxf(-5.f, pB * 0.25f)));
            if (j + la >= steps) scA = 0.f;
            if (j + lb >= steps) scB = 0.f;
            zacc += scA + scB;
            h2t sc2; sc2.x = (_Float16)scA; sc2.y = (_Float16)scB;
            vacc8(vA0, vB0, sc2, acc);
            kA0 = kA1; vA0 = vA1; kB0 = kB1; vB0 = vB1;
            kA1 = kA2; vA1 = vA2; kB1 = kB2; vB1 = vB2;
        }
    }

#pragma unroll
    for (int i = 0; i < 8; i++) {
        acc[i] += __shfl_xor(acc[i], 16, 64);
        acc[i] += __shfl_xor(acc[i], 32, 64);
    }
    zacc += __shfl_xor(zacc, 16, 64);
    zacc += __shfl_xor(zacc, 32, 64);

    const float inv = 1.f / zacc;                    // z of head lh>>1
    float r[8];
#pragma unroll
    for (int i = 0; i < 8; i++) r[i] = acc[i] * inv;
#pragma unroll
    for (int i = 0; i < 8; i++) {                    // mean over heads
        r[i] += __shfl_xor(r[i], 2, 64);
        r[i] += __shfl_xor(r[i], 4, 64);
        r[i] += __shfl_xor(r[i], 8, 64);
    }
    if (l < 2) {
        float4* op = (float4*)(out + (size_t)n * OD + l * 8);
        op[0] = make_float4(r[0] * 0.125f, r[1] * 0.125f, r[2] * 0.125f, r[3] * 0.125f);
        op[1] = make_float4(r[4] * 0.125f, r[5] * 0.125f, r[6] * 0.125f, r[7] * 0.125f);
    }
}

// ---------------- launch ------------------------------------------------------
extern "C" void kernel_launch(void* const* d_in, const int* in_sizes, int n_in,
                              void* d_out, int out_size, void* d_ws, size_t ws_size,
                              hipStream_t stream)
{
    const float* h  = (const float*)d_in[0];
    const float* Qw = (const float*)d_in[1];
    const float* Qb = (const float*)d_in[2];
    const float* Kw = (const float*)d_in[3];
    const float* Kb = (const float*)d_in[4];
    const float* Vw = (const float*)d_in[5];
    const float* Vb = (const float*)d_in[6];
    const int*   src = (const int*)d_in[7];
    const int*   dst = (const int*)d_in[8];

    char* ws = (char*)d_ws;
    _Float16* W16s  = (_Float16*)ws;                   ws += (size_t)NOUT * IND * 2;
    float*    b_all = (float*)ws;                      ws += 288 * 4;
    __half*   KVbuf = (__half*)ws;                     ws += (size_t)NNODES * 256 * 2;
    _Float16* Qs16  = (_Float16*)ws;                   ws += (size_t)NNODES * OD * 2;
    int*      offs   = (int*)ws;                       ws += (size_t)NNODES * 4;
    int*      count  = (int*)ws;                       ws += (size_t)NNODES * 4;
    unsigned short* counts = (unsigned short*)ws;      ws += (size_t)P1B * NBUCK * 2 + 64;
    unsigned int*   ebuck  = (unsigned int*)ws;        ws += (size_t)NBUCK * P1B * SCAP * 4;
    unsigned short* eidx16 = (unsigned short*)ws;      ws += (size_t)NBUCK * BCAP * 2;

    k1_scatter_w16<<<P1B + 1, 256, 0, stream>>>(
        src, dst, ebuck, counts, Qw, Qb, Kw, Kb, Vw, Vb, W16s, b_all);

    k2_proj_group<<<PB2 + NBUCK, 256, 0, stream>>>(
        h, W16s, b_all, KVbuf, Qs16, ebuck, counts, offs, count, eidx16);

    k3_gather<<<(NNODES + 3) / 4, 256, 0, stream>>>(
        (const uint4*)KVbuf, (const uint4*)Qs16, offs, count, eidx16, (float*)d_out);
}

// Round 15
// 226.281 us; speedup vs baseline: 1.4846x; 1.1692x over previous
//
#include <hip/hip_runtime.h>
#include <hip/hip_fp16.h>
#include <math.h>

#define NNODES 50000
#define IND    128
#define NH     8
#define OD     16
#define NEDGE  1600000
#define NOUT   272           // 128 K + 128 V + 16 Qsum
#define NBUCK  391           // dst>>7 buckets (128 nodes each)
#define BCAP   4608          // per-bucket output capacity
#define SCAP   56            // per (bucket,chunk) cell capacity
#define P1B    196           // edge chunks of 8192
#define WB     17            // W16 build blocks (2048 elements each)
#define PB2    782           // ceil(50000/64) proj tiles

typedef _Float16 half8 __attribute__((ext_vector_type(8)));
typedef _Float16 h2t   __attribute__((ext_vector_type(2)));
typedef float    floatx4 __attribute__((ext_vector_type(4)));

static __device__ __forceinline__ h2t u2h(unsigned int u) {
    union { unsigned int u; h2t h; } x; x.u = u; return x.h;
}
// acc[d] += vA[d]*scA + vB[d]*scB for 8 dims, fp32 accumulators.
static __device__ __forceinline__ void vacc8(uint4 vA, uint4 vB, h2t sc2, float* acc) {
    unsigned lo, hi;
    lo = __builtin_amdgcn_perm(vB.x, vA.x, 0x05040100u);
    hi = __builtin_amdgcn_perm(vB.x, vA.x, 0x07060302u);
    acc[0] = __builtin_amdgcn_fdot2(u2h(lo), sc2, acc[0], false);
    acc[1] = __builtin_amdgcn_fdot2(u2h(hi), sc2, acc[1], false);
    lo = __builtin_amdgcn_perm(vB.y, vA.y, 0x05040100u);
    hi = __builtin_amdgcn_perm(vB.y, vA.y, 0x07060302u);
    acc[2] = __builtin_amdgcn_fdot2(u2h(lo), sc2, acc[2], false);
    acc[3] = __builtin_amdgcn_fdot2(u2h(hi), sc2, acc[3], false);
    lo = __builtin_amdgcn_perm(vB.z, vA.z, 0x05040100u);
    hi = __builtin_amdgcn_perm(vB.z, vA.z, 0x07060302u);
    acc[4] = __builtin_amdgcn_fdot2(u2h(lo), sc2, acc[4], false);
    acc[5] = __builtin_amdgcn_fdot2(u2h(hi), sc2, acc[5], false);
    lo = __builtin_amdgcn_perm(vB.w, vA.w, 0x05040100u);
    hi = __builtin_amdgcn_perm(vB.w, vA.w, 0x07060302u);
    acc[6] = __builtin_amdgcn_fdot2(u2h(lo), sc2, acc[6], false);
    acc[7] = __builtin_amdgcn_fdot2(u2h(hi), sc2, acc[7], false);
}
static __device__ __forceinline__ float qdot(uint4 k, uint4 q, float p) {
    p = __builtin_amdgcn_fdot2(u2h(k.x), u2h(q.x), p, false);
    p = __builtin_amdgcn_fdot2(u2h(k.y), u2h(q.y), p, false);
    p = __builtin_amdgcn_fdot2(u2h(k.z), u2h(q.z), p, false);
    p = __builtin_amdgcn_fdot2(u2h(k.w), u2h(q.w), p, false);
    return p;
}

// ---------------- K1: scatter + PARALLEL W16s/b_all build ---------------------
// Blocks [0,P1B): 8192 edges; rank = LDS atomicAdd return; deterministic
// cell writes; no global atomics. Blocks [P1B,P1B+WB): W16 slice of 2048
// elements (8/thread) -- kills the single-block serial tail. Block P1B+WB:
// b_all.
__global__ __launch_bounds__(256) void k1_scatter_w16(
    const int* __restrict__ src, const int* __restrict__ dst,
    unsigned int* __restrict__ ebuck, unsigned short* __restrict__ counts,
    const float* __restrict__ Qw, const float* __restrict__ Qb,
    const float* __restrict__ Kw, const float* __restrict__ Kb,
    const float* __restrict__ Vw, const float* __restrict__ Vb,
    _Float16* __restrict__ W16s, float* __restrict__ b_all)
{
    const int t = threadIdx.x;

    if (blockIdx.x < P1B) {
        __shared__ int bcnt[NBUCK];
        for (int i = t; i < NBUCK; i += 256) bcnt[i] = 0;
        __syncthreads();

        const int blk = blockIdx.x;
        const int e0  = blk * 8192;
        const int nq  = (min(8192, NEDGE - e0)) >> 2;
        const int4* s4 = (const int4*)(src + e0);
        const int4* d4 = (const int4*)(dst + e0);

        uint4 ev4[8];
        unsigned int rkp[16];
#pragma unroll
        for (int j = 0; j < 8; j++) {
            int qi = j * 256 + t;
            if (qi < nq) {
                int4 ss = s4[qi];
                int4 dd = d4[qi];
                unsigned int v0 = (((unsigned)dd.x >> 7) << 23) | ((unsigned)ss.x << 7) | ((unsigned)dd.x & 127u);
                unsigned int v1 = (((unsigned)dd.y >> 7) << 23) | ((unsigned)ss.y << 7) | ((unsigned)dd.y & 127u);
                unsigned int v2 = (((unsigned)dd.z >> 7) << 23) | ((unsigned)ss.z << 7) | ((unsigned)dd.z & 127u);
                unsigned int v3 = (((unsigned)dd.w >> 7) << 23) | ((unsigned)ss.w << 7) | ((unsigned)dd.w & 127u);
                ev4[j] = make_uint4(v0, v1, v2, v3);
                unsigned r0 = atomicAdd(&bcnt[v0 >> 23], 1);
                unsigned r1 = atomicAdd(&bcnt[v1 >> 23], 1);
                unsigned r2 = atomicAdd(&bcnt[v2 >> 23], 1);
                unsigned r3 = atomicAdd(&bcnt[v3 >> 23], 1);
                rkp[2 * j]     = r0 | (r1 << 16);
                rkp[2 * j + 1] = r2 | (r3 << 16);
            }
        }
        __syncthreads();
#pragma unroll
        for (int j = 0; j < 8; j++) {
            int qi = j * 256 + t;
            if (qi < nq) {
                uint4 v = ev4[j];
                unsigned p0 = rkp[2 * j], p1 = rkp[2 * j + 1];
                unsigned r0 = p0 & 0xFFFFu, r1 = p0 >> 16;
                unsigned r2 = p1 & 0xFFFFu, r3 = p1 >> 16;
                if (r0 < SCAP) ebuck[((size_t)(v.x >> 23) * P1B + blk) * SCAP + r0] = v.x;
                if (r1 < SCAP) ebuck[((size_t)(v.y >> 23) * P1B + blk) * SCAP + r1] = v.y;
                if (r2 < SCAP) ebuck[((size_t)(v.z >> 23) * P1B + blk) * SCAP + r2] = v.z;
                if (r3 < SCAP) ebuck[((size_t)(v.w >> 23) * P1B + blk) * SCAP + r3] = v.w;
            }
        }
        __syncthreads();
        for (int i = t; i < NBUCK; i += 256)
            counts[(size_t)blk * NBUCK + i] = (unsigned short)min(bcnt[i], SCAP);
        return;
    }

    if (blockIdx.x < P1B + WB) {                       // ---- W16 slice --------
        const int s0 = (blockIdx.x - P1B) * 2048;
#pragma unroll
        for (int k = 0; k < 8; k++) {
            int i = s0 + k * 256 + t;                  // i < 34816 always
            int r = i >> 7, c = i & 127;
            float v;
            if (r < 128)       v = Kw[i];
            else if (r < 256)  v = Vw[i - 128 * IND];
            else {
                v = 0.f;
#pragma unroll
                for (int hh = 0; hh < NH; hh++) v += Qw[((hh << 4) + (r - 256)) * IND + c];
            }
            int ti = r >> 4, cl = r & 15, ks = c >> 5, quad = (c >> 3) & 3, e = c & 7;
            W16s[((((ti << 2) + ks) << 6) + quad * 16 + cl) * 8 + e] = (_Float16)v;
        }
        return;
    }

    // ---- b_all --------------------------------------------------------------
    for (int i = t; i < NOUT; i += 256) {
        float v;
        if (i < 128)      v = Kb[i];
        else if (i < 256) v = Vb[i - 128];
        else {
            v = 0.f;
#pragma unroll
            for (int hh = 0; hh < NH; hh++) v += Qb[(hh << 4) + (i - 256)];
        }
        b_all[i] = v;
    }
}

// ---------------- K2: MFMA proj (direct stores, R12) + grouping ---------------
__global__ __launch_bounds__(256) void k2_proj_group(
    const float* __restrict__ hmat,
    const _Float16* __restrict__ W16s, const float* __restrict__ b_all,
    __half* __restrict__ KVbuf, _Float16* __restrict__ Qs16,
    const unsigned int* __restrict__ ebuck, const unsigned short* __restrict__ counts,
    int* __restrict__ offs, int* __restrict__ count,
    unsigned short* __restrict__ eidx16)
{
    const int t = threadIdx.x;

    if (blockIdx.x < PB2) {                            // ---- projection -------
        const int wave = t >> 6;
        const int l    = t & 63;
        const int cl   = l & 15;
        const int quad = l >> 4;
        const int m0   = blockIdx.x * 64 + wave * 16;

        const int arow = min(m0 + cl, NNODES - 1);     // clamp OOB tail rows
        const float* ab = hmat + (size_t)arow * IND + quad * 8;
        half8 afrag[4];
#pragma unroll
        for (int ks = 0; ks < 4; ks++) {
            float4 x = *(const float4*)(ab + ks * 32);
            float4 y = *(const float4*)(ab + ks * 32 + 4);
            half8 o;
            o[0] = (_Float16)x.x; o[1] = (_Float16)x.y;
            o[2] = (_Float16)x.z; o[3] = (_Float16)x.w;
            o[4] = (_Float16)y.x; o[5] = (_Float16)y.y;
            o[6] = (_Float16)y.z; o[7] = (_Float16)y.w;
            afrag[ks] = o;
        }

        const int rowbase = m0 + quad * 4;
        const half8* Wf = (const half8*)W16s;

#pragma unroll 4
        for (int ti = 0; ti < 17; ti++) {
            floatx4 acc = {0.f, 0.f, 0.f, 0.f};
#pragma unroll
            for (int ks = 0; ks < 4; ks++)
                acc = __builtin_amdgcn_mfma_f32_16x16x32_f16(
                    afrag[ks], Wf[(((ti << 2) + ks) << 6) + l], acc, 0, 0, 0);

            const float bias = b_all[ti * 16 + cl];
            if (ti < 16) {
                const int col = ti * 16 + cl;
#pragma unroll
                for (int r = 0; r < 4; r++) {
                    int node = rowbase + r;
                    if (node < NNODES)
                        KVbuf[(size_t)node * 256 + col] = __float2half_rn(acc[r] + bias);
                }
            } else {
#pragma unroll
                for (int r = 0; r < 4; r++) {
                    int node = rowbase + r;
                    if (node < NNODES)
                        Qs16[(size_t)node * OD + cl] = (_Float16)(acc[r] + bias);
                }
            }
        }
        return;
    }

    // ---- grouping (R12) -----------------------------------------------------
    __shared__ int esh[BCAP];
    __shared__ int csh[256];
    __shared__ int cbase[256];
    __shared__ int sdc[256];
    __shared__ int cnt[128];
    __shared__ int sdn[128];
    __shared__ int base128[128];

    const int b = blockIdx.x - PB2;

    csh[t] = (t < P1B) ? (int)counts[(size_t)t * NBUCK + b] : 0;
    __syncthreads();
    sdc[t] = csh[t];
    __syncthreads();
    for (int ofs = 1; ofs < 256; ofs <<= 1) {
        int x = (t >= ofs) ? sdc[t - ofs] : 0;
        __syncthreads();
        sdc[t] += x;
        __syncthreads();
    }
    cbase[t] = sdc[t] - csh[t];
    __syncthreads();
    const int Eb = sdc[P1B - 1];

    const unsigned int* cells = ebuck + (size_t)b * P1B * SCAP;
    for (int idx = t; idx < P1B * SCAP; idx += 256) {
        int j = idx / SCAP;
        int r = idx - j * SCAP;
        if (r < csh[j]) {
            int p = cbase[j] + r;
            if (p < BCAP) esh[p] = (int)cells[idx];
        }
    }
    if (t < 128) cnt[t] = 0;
    __syncthreads();

    int rk[18];
#pragma unroll
    for (int j = 0; j < 18; j++) {
        int i = j * 256 + t;
        if (i < Eb) rk[j] = atomicAdd(&cnt[esh[i] & 127], 1);
    }
    __syncthreads();

    if (t < 128) sdn[t] = cnt[t];
    __syncthreads();
    for (int ofs = 1; ofs < 128; ofs <<= 1) {
        int x = 0;
        if (t < 128 && t >= ofs) x = sdn[t - ofs];
        __syncthreads();
        if (t < 128) sdn[t] += x;
        __syncthreads();
    }
    if (t < 128) {
        int excl = sdn[t] - cnt[t];
        base128[t] = excl;
        int node = (b << 7) + t;
        if (node < NNODES) { offs[node] = b * BCAP + excl; count[node] = cnt[t]; }
    }
    __syncthreads();

#pragma unroll
    for (int j = 0; j < 18; j++) {
        int i = j * 256 + t;
        if (i < Eb) {
            int v = esh[i];
            eidx16[(size_t)b * BCAP + base128[v & 127] + rk[j]] =
                (unsigned short)((v >> 7) & 0xFFFFu);
        }
    }
}

// ---------------- K3: gather-reduce, 16 lanes/edge (R12-verified) -------------
__global__ __launch_bounds__(256) void k3_gather(
    const uint4* __restrict__ KV4, const uint4* __restrict__ Qs16u4,
    const int* __restrict__ offs, const int* __restrict__ count,
    const unsigned short* __restrict__ eidx16,
    float* __restrict__ out)
{
    const int n = blockIdx.x * 4 + (threadIdx.x >> 6);
    const int l = threadIdx.x & 63;
    if (n >= NNODES) return;

    const int lh = l & 15;
    const int eg = l >> 4;
    const int la = 2 * eg, lb = 2 * eg + 1;

    const uint4 qh = Qs16u4[n * 2 + (lh & 1)];

    const int off   = offs[n];
    const int total = count[n] + 1;                  // + self-loop

    float acc[8] = {0.f, 0.f, 0.f, 0.f, 0.f, 0.f, 0.f, 0.f};
    float zacc = 0.f;

    for (int base = 0; base < total; base += 64) {
        const int gi = base + l;
        int id = n;                                  // gi==0 -> self-loop
        if (gi > 0) id = (gi < total) ? (int)eidx16[off + gi - 1] : 0;
        const int steps = min(64, total - base);

        int sA = __shfl(id, la, 64), sB = __shfl(id, lb, 64);
        uint4 kA0 = KV4[(size_t)sA * 32 + lh];
        uint4 vA0 = KV4[(size_t)sA * 32 + 16 + lh];
        uint4 kB0 = KV4[(size_t)sB * 32 + lh];
        uint4 vB0 = KV4[(size_t)sB * 32 + 16 + lh];
        int n1a = 8 + la, n1b = 8 + lb;
        int sA1 = __shfl(id, (n1a < 64) ? n1a : 0, 64);
        int sB1 = __shfl(id, (n1b < 64) ? n1b : 0, 64);
        uint4 kA1 = KV4[(size_t)sA1 * 32 + lh];
        uint4 vA1 = KV4[(size_t)sA1 * 32 + 16 + lh];
        uint4 kB1 = KV4[(size_t)sB1 * 32 + lh];
        uint4 vB1 = KV4[(size_t)sB1 * 32 + 16 + lh];

        for (int j = 0; j < steps; j += 8) {
            uint4 kA2, vA2, kB2, vB2;
            if (j + 16 < steps) {
                int n2a = j + 16 + la, n2b = j + 16 + lb;
                int sA2 = __shfl(id, (n2a < 64) ? n2a : 0, 64);
                int sB2 = __shfl(id, (n2b < 64) ? n2b : 0, 64);
                kA2 = KV4[(size_t)sA2 * 32 + lh];
                vA2 = KV4[(size_t)sA2 * 32 + 16 + lh];
                kB2 = KV4[(size_t)sB2 * 32 + lh];
                vB2 = KV4[(size_t)sB2 * 32 + 16 + lh];
            }
            float pA = qdot(kA0, qh, 0.f);
            float pB = qdot(kB0, qh, 0.f);
            pA += __shfl_xor(pA, 1, 64);
            pB += __shfl_xor(pB, 1, 64);
            float scA = __expf(fminf(5.f, fmaxf(-5.f, pA * 0.25f)));
            float scB = __expf(fminf(5.f, fmaxf(-5.f, pB * 0.25f)));
            if (j + la >= steps) scA = 0.f;
            if (j + lb >= steps) scB = 0.f;
            zacc += scA + scB;
            h2t sc2; sc2.x = (_Float16)scA; sc2.y = (_Float16)scB;
            vacc8(vA0, vB0, sc2, acc);
            kA0 = kA1; vA0 = vA1; kB0 = kB1; vB0 = vB1;
            kA1 = kA2; vA1 = vA2; kB1 = kB2; vB1 = vB2;
        }
    }

#pragma unroll
    for (int i = 0; i < 8; i++) {
        acc[i] += __shfl_xor(acc[i], 16, 64);
        acc[i] += __shfl_xor(acc[i], 32, 64);
    }
    zacc += __shfl_xor(zacc, 16, 64);
    zacc += __shfl_xor(zacc, 32, 64);

    const float inv = 1.f / zacc;                    // z of head lh>>1
    float r[8];
#pragma unroll
    for (int i = 0; i < 8; i++) r[i] = acc[i] * inv;
#pragma unroll
    for (int i = 0; i < 8; i++) {                    // mean over heads
        r[i] += __shfl_xor(r[i], 2, 64);
        r[i] += __shfl_xor(r[i], 4, 64);
        r[i] += __shfl_xor(r[i], 8, 64);
    }
    if (l < 2) {
        float4* op = (float4*)(out + (size_t)n * OD + l * 8);
        op[0] = make_float4(r[0] * 0.125f, r[1] * 0.125f, r[2] * 0.125f, r[3] * 0.125f);
        op[1] = make_float4(r[4] * 0.125f, r[5] * 0.125f, r[6] * 0.125f, r[7] * 0.125f);
    }
}

// ---------------- launch ------------------------------------------------------
extern "C" void kernel_launch(void* const* d_in, const int* in_sizes, int n_in,
                              void* d_out, int out_size, void* d_ws, size_t ws_size,
                              hipStream_t stream)
{
    const float* h  = (const float*)d_in[0];
    const float* Qw = (const float*)d_in[1];
    const float* Qb = (const float*)d_in[2];
    const float* Kw = (const float*)d_in[3];
    const float* Kb = (const float*)d_in[4];
    const float* Vw = (const float*)d_in[5];
    const float* Vb = (const float*)d_in[6];
    const int*   src = (const int*)d_in[7];
    const int*   dst = (const int*)d_in[8];

    char* ws = (char*)d_ws;
    _Float16* W16s  = (_Float16*)ws;                   ws += (size_t)NOUT * IND * 2;
    float*    b_all = (float*)ws;                      ws += 288 * 4;
    __half*   KVbuf = (__half*)ws;                     ws += (size_t)NNODES * 256 * 2;
    _Float16* Qs16  = (_Float16*)ws;                   ws += (size_t)NNODES * OD * 2;
    int*      offs   = (int*)ws;                       ws += (size_t)NNODES * 4;
    int*      count  = (int*)ws;                       ws += (size_t)NNODES * 4;
    unsigned short* counts = (unsigned short*)ws;      ws += (size_t)P1B * NBUCK * 2 + 64;
    unsigned int*   ebuck  = (unsigned int*)ws;        ws += (size_t)NBUCK * P1B * SCAP * 4;
    unsigned short* eidx16 = (unsigned short*)ws;      ws += (size_t)NBUCK * BCAP * 2;

    k1_scatter_w16<<<P1B + WB + 1, 256, 0, stream>>>(
        src, dst, ebuck, counts, Qw, Qb, Kw, Kb, Vw, Vb, W16s, b_all);

    k2_proj_group<<<PB2 + NBUCK, 256, 0, stream>>>(
        h, W16s, b_all, KVbuf, Qs16, ebuck, counts, offs, count, eidx16);

    k3_gather<<<(NNODES + 3) / 4, 256, 0, stream>>>(
        (const uint4*)KVbuf, (const uint4*)Qs16, offs, count, eidx16, (float*)d_out);
}